// Round 7
// baseline (198.824 us; speedup 1.0000x reference)
//
#include <hip/hip_runtime.h>
#include <math.h>
#include <stdint.h>

// Problem constants (fixed by the reference)
#define NFEAT 65536
#define DIM   512
#define D4    128          // DIM/4 (float4 groups over k)
#define NCLS  256
#define ROWS_PER_CLASS 256 // NFEAT/NCLS
#define EPSV  1e-8f

typedef float vf4 __attribute__((ext_vector_type(4)));

#define SFENCE() __builtin_amdgcn_sched_barrier(0)
#define AS1C(p) ((const __attribute__((address_space(1))) void*)(p))
#define AS3(p)  ((__attribute__((address_space(3))) void*)(p))

// ---------------------------------------------------------------------------
// kA: center-mean + normalize, feat streamed via LDS-DMA (global_load_lds).
//
// Why: every VGPR-return load variant (plain/NT/sc-bits, 16 waves or 8
// blocks/CU, 8- or 16-deep pipelines) runs this 134 MB stream at ~3.05 TB/s,
// matching m13's copy READ side (6.29 TB/s total = ~3.15 read) — consistent
// with a per-CU outstanding-line-fill cap on the vector-load return path
// (~35 lines x 128 B / ~375 ns = ~12 GB/s/CU). The write-only fill does
// 6.9 TB/s. global_load_lds lands data in LDS without the VGPR/L1 return
// path — the one mechanically different read datapath available.
//
// Geometry: 256 blocks x 1024 threads (16 waves). Class slab = 512 KB in 8
// chunks of 64 KB (32 rows). stage = 2 x 64 KB double buffer (128 KiB — the
// size the verified 8-phase GEMM example uses). Per chunk each wave issues
// 4 x global_load_lds width-16: wave w covers bytes q*16K + w*1K + lane*16.
// Raw s_barrier + counted vmcnt(4) keeps the next chunk's DMA in flight
// across the barrier (never drain to 0 mid-loop); sched_barrier(0) fences
// per guide rule #18.
//
// Reduction: chunk c == sub-window c; the 2 waves with sub==c sum rows 0..31
// ascending -> per-thread partials bit-identical to the previous kernel.
// red[]/wsum overlay the (dead) stage buffers: total LDS stays 128 KiB.
__global__ __launch_bounds__(1024)
void kA_center_norm(const float* __restrict__ feat, float4* __restrict__ nT4,
                    float* __restrict__ out) {
    const int cls  = blockIdx.x;
    const int t    = threadIdx.x;
    const int w    = t >> 6;              // wave 0..15
    const int lane = t & 63;
    const int col4 = t & 127;
    const int sub  = t >> 7;              // 0..7

    __shared__ char stage[2][65536];      // 128 KiB total

    const char* cbase = (const char*)feat + (size_t)cls * (ROWS_PER_CLASS * DIM * 4);
    const char* gsrc  = cbase + (size_t)w * 1024 + (size_t)lane * 16;

    // Issue chunk c (64 KB) into stage[p]: 4 DMA instructions per thread.
    // LDS dest is the WAVE-UNIFORM base (hardware adds lane*16 itself);
    // global src is per-lane.
#define ISSUE(c, p) do {                                                      \
        const char* g_ = gsrc + (size_t)(c) * 65536;                          \
        char* l_ = &stage[p][w * 1024];                                       \
        __builtin_amdgcn_global_load_lds(AS1C(g_),         AS3(l_),         16, 0, 0); \
        __builtin_amdgcn_global_load_lds(AS1C(g_ + 16384), AS3(l_ + 16384), 16, 0, 0); \
        __builtin_amdgcn_global_load_lds(AS1C(g_ + 32768), AS3(l_ + 32768), 16, 0, 0); \
        __builtin_amdgcn_global_load_lds(AS1C(g_ + 49152), AS3(l_ + 49152), 16, 0, 0); \
    } while (0)

    ISSUE(0, 0);
    ISSUE(1, 1);
    SFENCE();

    vf4 acc = (vf4){0.f, 0.f, 0.f, 0.f};

#pragma unroll
    for (int c = 0; c < 8; ++c) {
        // retire chunk c's 4 DMAs (chunk c+1's 4 stay in flight), all waves
        if (c < 7) asm volatile("s_waitcnt vmcnt(4)" ::: "memory");
        else       asm volatile("s_waitcnt vmcnt(0)" ::: "memory");
        SFENCE();
        __builtin_amdgcn_s_barrier();     // chunk c resident for ALL waves
        SFENCE();

        if (sub == c) {                   // 2 waves: sum rows 0..31 ascending
            const vf4* src = (const vf4*)&stage[c & 1][0];
#pragma unroll 8
            for (int r = 0; r < 32; ++r) acc += src[r * 128 + col4];
        }
        SFENCE();
        asm volatile("s_waitcnt lgkmcnt(0)" ::: "memory");  // my LDS reads done
        SFENCE();
        __builtin_amdgcn_s_barrier();     // nobody still reading stage[c&1]
        SFENCE();

        if (c < 6) ISSUE(c + 2, c & 1);   // refill the buffer just consumed
        SFENCE();
    }
#undef ISSUE

    // ---- epilogue: combine sub-partials, mean, normalize (stage is dead:
    //      overlay red on stage[0], wsum/s_inv on stage[1]) ----
    vf4*   red   = (vf4*)&stage[0][0];    // 16 KB
    float* wsum  = (float*)&stage[1][0];  // 2 floats
    float* s_inv = (float*)&stage[1][8];

    red[t] = acc;
    __syncthreads();

    vf4 cv = (vf4){0.f, 0.f, 0.f, 0.f};
    if (t < 128) {                        // t == col4 (sub == 0)
        cv = red[t];
#pragma unroll
        for (int s = 1; s < 8; ++s) cv += red[t + 128 * s];
        const float ms = 1.0f / (float)ROWS_PER_CLASS;  // mean (matches reference)
        cv *= ms;

        float ss = cv.x*cv.x + cv.y*cv.y + cv.z*cv.z + cv.w*cv.w;
#pragma unroll
        for (int o = 32; o > 0; o >>= 1) ss += __shfl_down(ss, o, 64);
        if ((t & 63) == 0) wsum[t >> 6] = ss;
    }
    __syncthreads();
    if (t == 0) {
        float nrm = sqrtf(wsum[0] + wsum[1]);
        *s_inv = 1.0f / fmaxf(nrm, EPSV); // torch CosineSimilarity eps semantics
        if (cls == 0) out[0] = 0.f;       // init for kB's atomicAdd (runs after kA)
    }
    __syncthreads();
    if (t < 128) {
        cv *= *s_inv;
        nT4[(size_t)col4 * NCLS + cls] = make_float4(cv.x, cv.y, cv.z, cv.w);
    }
}

// ---------------------------------------------------------------------------
// kB: fused column-min + global sum, 1024 threads: i = t&255 row index,
// pt = t>>8 splits the 128 k-groups 4 ways. nT4 (512 KB) is L2/L3-resident.
// One atomicAdd per block. Unchanged (verified absmax 0.0).
__global__ __launch_bounds__(1024)
void kB_min_sum(const float4* __restrict__ nT4, float* __restrict__ out) {
    const int j = blockIdx.x;
    const int t = threadIdx.x;

    __shared__ float4 bj[D4];             // 2 KB
    __shared__ float  pacc[4][256];       // 4 KB
    __shared__ float  wmin[4];
    if (t < D4) bj[t] = nT4[(size_t)t * NCLS + j];
    __syncthreads();

    const int i  = t & 255;
    const int pt = t >> 8;                // 0..3
    const int g0 = pt * 32;
    float dacc = 0.f;
#pragma unroll 8
    for (int g = g0; g < g0 + 32; ++g) {
        float4 a = nT4[(size_t)g * NCLS + i];   // coalesced, L2/L3-resident
        float4 b = bj[g];                        // LDS broadcast
        dacc += a.x*b.x + a.y*b.y + a.z*b.z + a.w*b.w;
    }
    pacc[pt][i] = dacc;
    __syncthreads();

    if (t < 256) {
        float d = pacc[0][i] + pacc[1][i] + pacc[2][i] + pacc[3][i];
        if (i == j) d = INFINITY;         // exclude diagonal
#pragma unroll
        for (int o = 32; o > 0; o >>= 1) d = fminf(d, __shfl_down(d, o, 64));
        if ((i & 63) == 0) wmin[i >> 6] = d;
    }
    __syncthreads();
    if (t == 0) {
        float m = fminf(fminf(wmin[0], wmin[1]), fminf(wmin[2], wmin[3]));
        atomicAdd(out, 1.0f - m);         // device-scope by default on gfx950
    }
}

// ---------------------------------------------------------------------------
extern "C" void kernel_launch(void* const* d_in, const int* in_sizes, int n_in,
                              void* d_out, int out_size, void* d_ws, size_t ws_size,
                              hipStream_t stream) {
    const float* feat = (const float*)d_in[0];
    // d_in[1] (label) is unused: contiguous unique class blocks -> identity mask.
    float* out = (float*)d_out;

    // Workspace: transposed normalized centers (512 KB), written in full by
    // kA before kB reads it (kernel-boundary sync + coherence).
    float* nT4f = (float*)d_ws;

    kA_center_norm <<<NCLS, 1024, 0, stream>>>(feat, (float4*)nT4f, out);
    kB_min_sum     <<<NCLS, 1024, 0, stream>>>((const float4*)nT4f, out);
}

// Round 8
// 187.769 us; speedup vs baseline: 1.0589x; 1.0589x over previous
//
#include <hip/hip_runtime.h>
#include <math.h>

// Problem constants (fixed by the reference)
#define NFEAT 65536
#define DIM   512
#define D4    128          // DIM/4 (float4 groups over k)
#define NCLS  256
#define ROWS_PER_CLASS 256 // NFEAT/NCLS
#define EPSV  1e-8f

// Native clang vector type (maps to 4 consecutive VGPRs in inline asm).
typedef float vf4 __attribute__((ext_vector_type(4)));

// Streaming load: sc0 sc1 nt — best measured policy (R6: 186.7 us vs 188.2
// plain nt, 198.2 cached). NOTE (R7 post-mortem): the feat read stream is
// capped at ~3.1 TB/s by the chip's outstanding-read-tag limit (~32-40
// line-fills/CU x 128 B / ~375 ns ≈ 12 GB/s/CU); four orthogonal mechanisms
// (deep ILP, grid-flat decomposition, sc-bit policies, LDS-DMA) all land on
// the same number, while the write-only fill does 6.9 TB/s (writes are
// posted, no tags). This kernel sits at that read roofline.
__device__ __forceinline__ vf4 ld_stream(const vf4* p) {
    vf4 r;
    asm volatile("global_load_dwordx4 %0, %1, off sc0 sc1 nt"
                 : "=v"(r) : "v"(p));
    return r;
}
// Inline-asm loads are invisible to the compiler's vmcnt bookkeeping -> we
// count them ourselves. sched_barrier(0) after each wait per guide rule #18
// (compiler otherwise hoists register-only consumers past an asm s_waitcnt).
#define WAITCNT(n) do { \
    asm volatile("s_waitcnt vmcnt(" #n ")"); \
    __builtin_amdgcn_sched_barrier(0); \
} while (0)

// ---------------------------------------------------------------------------
// kA: fused center-mean + normalize (256 blocks x 1024 threads, 16 waves/CU;
// thread t: col4 = t&127, sub = t>>7, 32 contiguous rows each).
// Counted-vmcnt 2-deep pipeline of 8-load batches; accumulation order is
// rows 0..31 ascending in batches of 8 -> bit-identical across rounds.
__global__ __launch_bounds__(1024)
void kA_center_norm(const vf4* __restrict__ feat4, float4* __restrict__ nT4,
                    float* __restrict__ out) {
    const int cls  = blockIdx.x;
    const int t    = threadIdx.x;
    const int col4 = t & 127;
    const int sub  = t >> 7;              // 0..7
    const int row0 = cls * ROWS_PER_CLASS + sub * 32;

    const vf4* p = feat4 + (size_t)row0 * D4 + col4;

    vf4 va[8], vb[8];
    // batch 0 (rows 0-7) and batch 1 (rows 8-15): 16 loads in flight
#pragma unroll
    for (int k = 0; k < 8; ++k) va[k] = ld_stream(p + (size_t)k * D4);
#pragma unroll
    for (int k = 0; k < 8; ++k) vb[k] = ld_stream(p + (size_t)(8 + k) * D4);

    vf4 acc = (vf4){0.f, 0.f, 0.f, 0.f};

    WAITCNT(8);                           // batch 0 landed
#pragma unroll
    for (int k = 0; k < 8; ++k) acc += va[k];
#pragma unroll
    for (int k = 0; k < 8; ++k) va[k] = ld_stream(p + (size_t)(16 + k) * D4);

    WAITCNT(8);                           // batch 1 landed
#pragma unroll
    for (int k = 0; k < 8; ++k) acc += vb[k];
#pragma unroll
    for (int k = 0; k < 8; ++k) vb[k] = ld_stream(p + (size_t)(24 + k) * D4);

    WAITCNT(8);                           // batch 2 landed
#pragma unroll
    for (int k = 0; k < 8; ++k) acc += va[k];

    WAITCNT(0);                           // batch 3 landed
#pragma unroll
    for (int k = 0; k < 8; ++k) acc += vb[k];

    __shared__ vf4 red[1024];             // 16 KB
    red[t] = acc;
    __syncthreads();

    __shared__ float wsum[2];
    __shared__ float s_inv;
    vf4 c = (vf4){0.f, 0.f, 0.f, 0.f};
    if (t < 128) {                        // t == col4 here (sub == 0)
        c = red[t];
#pragma unroll
        for (int s = 1; s < 8; ++s) c += red[t + 128 * s];
        const float ms = 1.0f / (float)ROWS_PER_CLASS;  // mean (matches reference)
        c *= ms;

        float ss = c.x*c.x + c.y*c.y + c.z*c.z + c.w*c.w;
#pragma unroll
        for (int o = 32; o > 0; o >>= 1) ss += __shfl_down(ss, o, 64);
        if ((t & 63) == 0) wsum[t >> 6] = ss;
    }
    __syncthreads();
    if (t == 0) {
        float nrm = sqrtf(wsum[0] + wsum[1]);
        s_inv = 1.0f / fmaxf(nrm, EPSV);  // torch CosineSimilarity eps semantics
        if (cls == 0) out[0] = 0.f;       // init for kB's atomicAdd (runs after kA)
    }
    __syncthreads();
    if (t < 128) {
        c *= s_inv;
        nT4[(size_t)col4 * NCLS + cls] = make_float4(c.x, c.y, c.z, c.w);
    }
}

// ---------------------------------------------------------------------------
// kB: fused column-min + global sum, 1024 threads: i = t&255 row index,
// pt = t>>8 splits the 128 k-groups 4 ways. nT4 (512 KB) is L2/L3-resident
// (normal cached loads — re-read 256x, allocation is what we want). One
// atomicAdd per block. Verified absmax 0.0.
__global__ __launch_bounds__(1024)
void kB_min_sum(const float4* __restrict__ nT4, float* __restrict__ out) {
    const int j = blockIdx.x;
    const int t = threadIdx.x;

    __shared__ float4 bj[D4];             // 2 KB
    __shared__ float  pacc[4][256];       // 4 KB
    __shared__ float  wmin[4];
    if (t < D4) bj[t] = nT4[(size_t)t * NCLS + j];
    __syncthreads();

    const int i  = t & 255;
    const int pt = t >> 8;                // 0..3
    const int g0 = pt * 32;
    float dacc = 0.f;
#pragma unroll 8
    for (int g = g0; g < g0 + 32; ++g) {
        float4 a = nT4[(size_t)g * NCLS + i];   // coalesced, L2/L3-resident
        float4 b = bj[g];                        // LDS broadcast
        dacc += a.x*b.x + a.y*b.y + a.z*b.z + a.w*b.w;
    }
    pacc[pt][i] = dacc;
    __syncthreads();

    if (t < 256) {
        float d = pacc[0][i] + pacc[1][i] + pacc[2][i] + pacc[3][i];
        if (i == j) d = INFINITY;         // exclude diagonal
#pragma unroll
        for (int o = 32; o > 0; o >>= 1) d = fminf(d, __shfl_down(d, o, 64));
        if ((i & 63) == 0) wmin[i >> 6] = d;
    }
    __syncthreads();
    if (t == 0) {
        float m = fminf(fminf(wmin[0], wmin[1]), fminf(wmin[2], wmin[3]));
        atomicAdd(out, 1.0f - m);         // device-scope by default on gfx950
    }
}

// ---------------------------------------------------------------------------
extern "C" void kernel_launch(void* const* d_in, const int* in_sizes, int n_in,
                              void* d_out, int out_size, void* d_ws, size_t ws_size,
                              hipStream_t stream) {
    const float* feat = (const float*)d_in[0];
    // d_in[1] (label) is unused: contiguous unique class blocks -> identity mask.
    float* out = (float*)d_out;

    // Workspace: transposed normalized centers (512 KB), written in full by
    // kA before kB reads it (kernel-boundary sync + coherence).
    float* nT4f = (float*)d_ws;

    kA_center_norm <<<NCLS, 1024, 0, stream>>>((const vf4*)feat, (float4*)nT4f, out);
    kB_min_sum     <<<NCLS, 1024, 0, stream>>>((const float4*)nT4f, out);
}